// Round 1
// baseline (389.419 us; speedup 1.0000x reference)
//
#include <hip/hip_runtime.h>

#define LOG2E 1.44269504088896340736f

__device__ __forceinline__ float vexp2(float x){ float r; asm("v_exp_f32 %0, %1" : "=v"(r) : "v"(x)); return r; }
__device__ __forceinline__ float vrcp (float x){ float r; asm("v_rcp_f32 %0, %1" : "=v"(r) : "v"(x)); return r; }

// sigmoid for gates i,f,o; tanh (=2*sigmoid(2x)-1) for gate g, selected branchlessly
__device__ __forceinline__ float gate_act(float x, bool is_g){
  float xx = is_g ? x + x : x;
  float e = vexp2(xx * (-LOG2E));
  float s = vrcp(1.0f + e);
  return is_g ? s + s - 1.0f : s;
}
__device__ __forceinline__ float tanh_f(float x){
  float e = vexp2(x * (-2.0f * LOG2E));
  float s = vrcp(1.0f + e);
  return s + s - 1.0f;
}

__global__ void __launch_bounds__(64, 3)
lstm_ae_fused(const float* __restrict__ x,
              const float* __restrict__ e1Wi, const float* __restrict__ e1Wh, const float* __restrict__ e1bi, const float* __restrict__ e1bh,
              const float* __restrict__ e2Wi, const float* __restrict__ e2Wh, const float* __restrict__ e2bi, const float* __restrict__ e2bh,
              const float* __restrict__ e3Wi, const float* __restrict__ e3Wh, const float* __restrict__ e3bi, const float* __restrict__ e3bh,
              const float* __restrict__ d1Wi, const float* __restrict__ d1Wh, const float* __restrict__ d1bi, const float* __restrict__ d1bh,
              const float* __restrict__ d2Wi, const float* __restrict__ d2Wh, const float* __restrict__ d2bi, const float* __restrict__ d2bh,
              const float* __restrict__ d3Wi, const float* __restrict__ d3Wh, const float* __restrict__ d3bi, const float* __restrict__ d3bh,
              const float* __restrict__ Wout, const float* __restrict__ bout,
              float* __restrict__ out)
{
  const int lane = threadIdx.x;          // 0..63, one wave per block
  const int b    = blockIdx.x;           // one batch element per wave
  const float* __restrict__ xb = x   + (size_t)b * (128*32);
  float*       __restrict__ ob = out + (size_t)b * (128*32);

  // ================= encoder weights (per-lane = per-gate rows) =================
  float w1i[32], w1h[16], b1;
  {
    const int g = lane;                              // 4h = 64 gates
    #pragma unroll
    for (int k=0;k<32;++k) w1i[k] = e1Wi[g*32+k];
    #pragma unroll
    for (int k=0;k<16;++k) w1h[k] = e1Wh[g*16+k];
    b1 = e1bi[g] + e1bh[g];
  }
  float w2i[16], w2h[4], b2;
  {
    const int g = lane & 15;                         // 4h = 16 gates (duplicated)
    #pragma unroll
    for (int k=0;k<16;++k) w2i[k] = e2Wi[g*16+k];
    #pragma unroll
    for (int k=0;k<4;++k)  w2h[k] = e2Wh[g*4+k];
    b2 = e2bi[g] + e2bh[g];
  }
  float w3i[4], w3h, b3;
  {
    const int g = lane & 3;                          // 4h = 4 gates (duplicated)
    #pragma unroll
    for (int k=0;k<4;++k) w3i[k] = e3Wi[g*4+k];
    w3h = e3Wh[g];
    b3 = e3bi[g] + e3bh[g];
  }

  const bool isg1 = (lane >= 32) && (lane < 48);             // gate 'g' chunk, h=16
  const bool isg2 = ((lane & 15) >= 8) && ((lane & 15) < 12);// h=4
  const bool isg3 = ((lane & 3) == 2);                       // h=1

  float h1r[16], h2r[4], h3r = 0.f, c1 = 0.f, c2 = 0.f, c3 = 0.f;
  #pragma unroll
  for (int k=0;k<16;++k) h1r[k] = 0.f;
  #pragma unroll
  for (int k=0;k<4;++k)  h2r[k] = 0.f;

  #pragma unroll 2
  for (int t=0;t<128;++t){
    const float* __restrict__ xt = xb + t*32;        // wave-uniform address
    // ---- e1: din=32, h=16
    float a0 = b1, a1 = 0.f;
    #pragma unroll
    for (int k=0;k<32;k+=2){ a0 = fmaf(w1i[k], xt[k], a0); a1 = fmaf(w1i[k+1], xt[k+1], a1); }
    #pragma unroll
    for (int k=0;k<16;k+=2){ a0 = fmaf(w1h[k], h1r[k], a0); a1 = fmaf(w1h[k+1], h1r[k+1], a1); }
    float v = gate_act(a0 + a1, isg1);
    float f = __shfl(v, lane+16, 64);
    float g = __shfl(v, lane+32, 64);
    float o = __shfl(v, lane+48, 64);
    c1 = fmaf(f, c1, v*g);                           // valid on lanes 0..15
    float h1 = o * tanh_f(c1);
    #pragma unroll
    for (int k=0;k<16;++k) h1r[k] = __shfl(h1, k, 64);
    // ---- e2: din=16, h=4
    a0 = b2; a1 = 0.f;
    #pragma unroll
    for (int k=0;k<16;k+=2){ a0 = fmaf(w2i[k], h1r[k], a0); a1 = fmaf(w2i[k+1], h1r[k+1], a1); }
    #pragma unroll
    for (int k=0;k<4;++k) a0 = fmaf(w2h[k], h2r[k], a0);
    v = gate_act(a0 + a1, isg2);
    f = __shfl(v, lane+4, 64);
    g = __shfl(v, lane+8, 64);
    o = __shfl(v, lane+12, 64);
    c2 = fmaf(f, c2, v*g);
    float h2 = o * tanh_f(c2);
    #pragma unroll
    for (int k=0;k<4;++k) h2r[k] = __shfl(h2, k, 64);
    // ---- e3: din=4, h=1
    float a = b3;
    #pragma unroll
    for (int k=0;k<4;++k) a = fmaf(w3i[k], h2r[k], a);
    a = fmaf(w3h, h3r, a);
    v = gate_act(a, isg3);
    f = __shfl(v, lane+1, 64);
    g = __shfl(v, lane+2, 64);
    o = __shfl(v, lane+3, 64);
    c3 = fmaf(f, c3, v*g);
    h3r = __shfl(o * tanh_f(c3), 0, 64);
  }
  const float enc = h3r;

  // ================= decoder weights =================
  float p1, wd1h[4];
  {
    const int g = lane & 15;                         // d1: din=1, h=4
    float wi = d1Wi[g];
    #pragma unroll
    for (int k=0;k<4;++k) wd1h[k] = d1Wh[g*4+k];
    p1 = fmaf(wi, enc, d1bi[g] + d1bh[g]);           // input term constant over t
  }
  float wd2i[4], wd2h[8], bd2;
  {
    const int g = lane & 31;                         // d2: din=4, h=8
    #pragma unroll
    for (int k=0;k<4;++k) wd2i[k] = d2Wi[g*4+k];
    #pragma unroll
    for (int k=0;k<8;++k) wd2h[k] = d2Wh[g*8+k];
    bd2 = d2bi[g] + d2bh[g];
  }
  float wd3i[8], wd3h[16], bd3;
  {
    const int g = lane;                              // d3: din=8, h=16
    #pragma unroll
    for (int k=0;k<8;++k)  wd3i[k] = d3Wi[g*8+k];
    #pragma unroll
    for (int k=0;k<16;++k) wd3h[k] = d3Wh[g*16+k];
    bd3 = d3bi[g] + d3bh[g];
  }
  float wo[16], bo;
  {
    const int g = lane & 31;                         // final linear: 32 outputs
    #pragma unroll
    for (int k=0;k<16;++k) wo[k] = Wout[g*16+k];
    bo = bout[g];
  }

  const bool gd1 = ((lane & 15) >= 8) && ((lane & 15) < 12); // h=4
  const bool gd2 = ((lane & 31) >= 16) && ((lane & 31) < 24);// h=8
  const bool gd3 = (lane >= 32) && (lane < 48);              // h=16

  float hd1[4], hd2[8], hd3[16];
  #pragma unroll
  for (int k=0;k<4;++k)  hd1[k] = 0.f;
  #pragma unroll
  for (int k=0;k<8;++k)  hd2[k] = 0.f;
  #pragma unroll
  for (int k=0;k<16;++k) hd3[k] = 0.f;
  c1 = c2 = c3 = 0.f;

  #pragma unroll 2
  for (int t=0;t<128;++t){
    // ---- d1: din=1 (constant input), h=4
    float a = p1;
    #pragma unroll
    for (int k=0;k<4;++k) a = fmaf(wd1h[k], hd1[k], a);
    float v = gate_act(a, gd1);
    float f = __shfl(v, lane+4, 64);
    float g = __shfl(v, lane+8, 64);
    float o = __shfl(v, lane+12, 64);
    c1 = fmaf(f, c1, v*g);
    float h1 = o * tanh_f(c1);
    #pragma unroll
    for (int k=0;k<4;++k) hd1[k] = __shfl(h1, k, 64);
    // ---- d2: din=4, h=8
    float a0 = bd2, a1 = 0.f;
    #pragma unroll
    for (int k=0;k<4;++k) a0 = fmaf(wd2i[k], hd1[k], a0);
    #pragma unroll
    for (int k=0;k<8;k+=2){ a0 = fmaf(wd2h[k], hd2[k], a0); a1 = fmaf(wd2h[k+1], hd2[k+1], a1); }
    v = gate_act(a0 + a1, gd2);
    f = __shfl(v, lane+8, 64);
    g = __shfl(v, lane+16, 64);
    o = __shfl(v, lane+24, 64);
    c2 = fmaf(f, c2, v*g);
    float h2 = o * tanh_f(c2);
    #pragma unroll
    for (int k=0;k<8;++k) hd2[k] = __shfl(h2, k, 64);
    // ---- d3: din=8, h=16
    a0 = bd3; a1 = 0.f;
    #pragma unroll
    for (int k=0;k<8;k+=2){  a0 = fmaf(wd3i[k], hd2[k], a0); a1 = fmaf(wd3i[k+1], hd2[k+1], a1); }
    #pragma unroll
    for (int k=0;k<16;k+=2){ a0 = fmaf(wd3h[k], hd3[k], a0); a1 = fmaf(wd3h[k+1], hd3[k+1], a1); }
    v = gate_act(a0 + a1, gd3);
    f = __shfl(v, lane+16, 64);
    g = __shfl(v, lane+32, 64);
    o = __shfl(v, lane+48, 64);
    c3 = fmaf(f, c3, v*g);
    float h3 = o * tanh_f(c3);
    #pragma unroll
    for (int k=0;k<16;++k) hd3[k] = __shfl(h3, k, 64);
    // ---- final linear 16->32, coalesced store
    float ov = bo;
    #pragma unroll
    for (int k=0;k<16;++k) ov = fmaf(wo[k], hd3[k], ov);
    if (lane < 32) ob[t*32 + lane] = ov;
  }
}

extern "C" void kernel_launch(void* const* d_in, const int* in_sizes, int n_in,
                              void* d_out, int out_size, void* d_ws, size_t ws_size,
                              hipStream_t stream) {
  (void)in_sizes; (void)n_in; (void)d_ws; (void)ws_size; (void)out_size;
  const float* x    = (const float*)d_in[0];
  const float* e1Wi = (const float*)d_in[1];
  const float* e1Wh = (const float*)d_in[2];
  const float* e1bi = (const float*)d_in[3];
  const float* e1bh = (const float*)d_in[4];
  const float* e2Wi = (const float*)d_in[5];
  const float* e2Wh = (const float*)d_in[6];
  const float* e2bi = (const float*)d_in[7];
  const float* e2bh = (const float*)d_in[8];
  const float* e3Wi = (const float*)d_in[9];
  const float* e3Wh = (const float*)d_in[10];
  const float* e3bi = (const float*)d_in[11];
  const float* e3bh = (const float*)d_in[12];
  const float* d1Wi = (const float*)d_in[13];
  const float* d1Wh = (const float*)d_in[14];
  const float* d1bi = (const float*)d_in[15];
  const float* d1bh = (const float*)d_in[16];
  const float* d2Wi = (const float*)d_in[17];
  const float* d2Wh = (const float*)d_in[18];
  const float* d2bi = (const float*)d_in[19];
  const float* d2bh = (const float*)d_in[20];
  const float* d3Wi = (const float*)d_in[21];
  const float* d3Wh = (const float*)d_in[22];
  const float* d3bi = (const float*)d_in[23];
  const float* d3bh = (const float*)d_in[24];
  const float* Wout = (const float*)d_in[25];
  const float* boutp= (const float*)d_in[26];
  float* out = (float*)d_out;

  lstm_ae_fused<<<4096, 64, 0, stream>>>(x,
      e1Wi, e1Wh, e1bi, e1bh,
      e2Wi, e2Wh, e2bi, e2bh,
      e3Wi, e3Wh, e3bi, e3bh,
      d1Wi, d1Wh, d1bi, d1bh,
      d2Wi, d2Wh, d2bi, d2bh,
      d3Wi, d3Wh, d3bi, d3bh,
      Wout, boutp, out);
}

// Round 2
// 276.013 us; speedup vs baseline: 1.4109x; 1.4109x over previous
//
#include <hip/hip_runtime.h>

#define LOG2E 1.44269504088896340736f

__device__ __forceinline__ float vexp2(float x){ float r; asm("v_exp_f32 %0, %1" : "=v"(r) : "v"(x)); return r; }
__device__ __forceinline__ float vrcp (float x){ float r; asm("v_rcp_f32 %0, %1" : "=v"(r) : "v"(x)); return r; }
__device__ __forceinline__ float rl(float v, int l){
  return __int_as_float(__builtin_amdgcn_readlane(__float_as_int(v), l));
}
template<int XM> __device__ __forceinline__ float swx(float v){
  return __int_as_float(__builtin_amdgcn_ds_swizzle(__float_as_int(v), (XM<<10)|0x1F));
}
__device__ __forceinline__ float sigm(float x){ return vrcp(1.0f + vexp2(x * (-LOG2E))); }
__device__ __forceinline__ float tanh_f(float x){
  float s = vrcp(1.0f + vexp2(x * (-2.0f*LOG2E)));
  return s + s - 1.0f;
}

__global__ void __launch_bounds__(64, 4)
lstm_ae_fused(const float* __restrict__ x,
              const float* __restrict__ e1Wi, const float* __restrict__ e1Wh, const float* __restrict__ e1bi, const float* __restrict__ e1bh,
              const float* __restrict__ e2Wi, const float* __restrict__ e2Wh, const float* __restrict__ e2bi, const float* __restrict__ e2bh,
              const float* __restrict__ e3Wi, const float* __restrict__ e3Wh, const float* __restrict__ e3bi, const float* __restrict__ e3bh,
              const float* __restrict__ d1Wi, const float* __restrict__ d1Wh, const float* __restrict__ d1bi, const float* __restrict__ d1bh,
              const float* __restrict__ d2Wi, const float* __restrict__ d2Wh, const float* __restrict__ d2bi, const float* __restrict__ d2bh,
              const float* __restrict__ d3Wi, const float* __restrict__ d3Wh, const float* __restrict__ d3bi, const float* __restrict__ d3bh,
              const float* __restrict__ Wout, const float* __restrict__ bout,
              float* __restrict__ out)
{
  const int lane = threadIdx.x;          // 0..63, one wave per block
  const int b    = blockIdx.x;           // one batch element per wave
  const float* __restrict__ xb = x   + (size_t)b * (128*32);
  float*       __restrict__ ob = out + (size_t)b * (128*32);

  // gate-role masks (PyTorch order i,f,g,o): g-chunk lanes get tanh
  const bool isg1 = (lane >= 32) && (lane < 48);              // e1/d3 h=16
  const bool isg2 = ((lane & 15) >= 8) && ((lane & 15) < 12); // e2/d1 h=4
  const bool isg3 = ((lane & 3) == 2);                        // e3 h=1
  const bool isgD2= ((lane & 31) >= 16) && ((lane & 31) < 24);// d2 h=8

  const float A1 = isg1 ? 2.f : 1.f,  B1 = isg1 ? -1.f : 0.f;
  const float A2 = isg2 ? 2.f : 1.f,  B2 = isg2 ? -1.f : 0.f;
  const float A3 = isg3 ? 2.f : 1.f,  B3 = isg3 ? -1.f : 0.f;
  const float AD2= isgD2? 2.f : 1.f,  BD2= isgD2? -1.f : 0.f;

  // ======================= ENCODER =======================
  {
    // weights (g-gate rows pre-scaled x2 so tanh(x) = 2*sigm(2x)-1 needs no extra mul)
    float w1i[32], w1h[16], eb1;
    {
      const int g = lane;
      #pragma unroll
      for (int k=0;k<32;++k) w1i[k] = e1Wi[g*32+k]*A1;
      #pragma unroll
      for (int k=0;k<16;++k) w1h[k] = e1Wh[g*16+k]*A1;
      eb1 = (e1bi[g] + e1bh[g])*A1;
    }
    float w2i[16], w2h[4], eb2;
    {
      const int g = lane & 15;
      #pragma unroll
      for (int k=0;k<16;++k) w2i[k] = e2Wi[g*16+k]*A2;
      #pragma unroll
      for (int k=0;k<4;++k)  w2h[k] = e2Wh[g*4+k]*A2;
      eb2 = (e2bi[g] + e2bh[g])*A2;
    }
    float w3i[4], w3h, eb3;
    {
      const int g = lane & 3;
      #pragma unroll
      for (int k=0;k<4;++k) w3i[k] = e3Wi[g*4+k]*A3;
      w3h = e3Wh[g]*A3;
      eb3 = (e3bi[g] + e3bh[g])*A3;
    }

    float h1s[16], h2s[4], h3s = 0.f, c1 = 0.f, c2 = 0.f, c3 = 0.f;
    #pragma unroll
    for (int k=0;k<16;++k) h1s[k] = 0.f;
    #pragma unroll
    for (int k=0;k<4;++k)  h2s[k] = 0.f;

    #pragma unroll 2
    for (int t=0;t<128;++t){
      const float* __restrict__ xt = xb + t*32;     // wave-uniform -> scalar loads
      float xv[32];
      #pragma unroll
      for (int k=0;k<32;++k) xv[k] = xt[k];

      // ---- e1: din=32, h=16 (gate-per-lane, 64 gates)
      float a0=eb1, a1=0.f, a2=0.f, a3=0.f;
      #pragma unroll
      for (int k=0;k<32;k+=4){
        a0 = fmaf(w1i[k  ], xv[k  ], a0);
        a1 = fmaf(w1i[k+1], xv[k+1], a1);
        a2 = fmaf(w1i[k+2], xv[k+2], a2);
        a3 = fmaf(w1i[k+3], xv[k+3], a3);
      }
      #pragma unroll
      for (int k=0;k<16;k+=4){
        a0 = fmaf(w1h[k  ], h1s[k  ], a0);
        a1 = fmaf(w1h[k+1], h1s[k+1], a1);
        a2 = fmaf(w1h[k+2], h1s[k+2], a2);
        a3 = fmaf(w1h[k+3], h1s[k+3], a3);
      }
      float v = fmaf(sigm((a0+a1)+(a2+a3)), A1, B1);
      float f = swx<16>(v);
      float g = __shfl_xor(v, 32, 64);
      float o = __shfl_xor(f, 32, 64);
      c1 = fmaf(f, c1, v*g);                        // valid lanes 0..15
      float h1 = o * tanh_f(c1);
      #pragma unroll
      for (int k=0;k<16;++k) h1s[k] = rl(h1, k);    // -> SGPRs

      // ---- e2: din=16, h=4
      a0 = eb2; a1 = 0.f;
      #pragma unroll
      for (int k=0;k<16;k+=2){ a0 = fmaf(w2i[k], h1s[k], a0); a1 = fmaf(w2i[k+1], h1s[k+1], a1); }
      #pragma unroll
      for (int k=0;k<4;k+=2){ a0 = fmaf(w2h[k], h2s[k], a0); a1 = fmaf(w2h[k+1], h2s[k+1], a1); }
      v = fmaf(sigm(a0+a1), A2, B2);
      f = swx<4>(v);  g = swx<8>(v);  o = swx<12>(v);
      c2 = fmaf(f, c2, v*g);                        // valid lanes 0..3
      float h2 = o * tanh_f(c2);
      #pragma unroll
      for (int k=0;k<4;++k) h2s[k] = rl(h2, k);

      // ---- e3: din=4, h=1
      float a = eb3;
      #pragma unroll
      for (int k=0;k<4;++k) a = fmaf(w3i[k], h2s[k], a);
      a = fmaf(w3h, h3s, a);
      v = fmaf(sigm(a), A3, B3);
      f = swx<1>(v);  g = swx<2>(v);  o = swx<3>(v);
      c3 = fmaf(f, c3, v*g);                        // valid lane 0
      h3s = rl(o * tanh_f(c3), 0);
    }

    // stash enc in a pinned place for the decoder scope via shared-nothing: just fall through
    // (h3s survives scope end below)
    __attribute__((unused)) volatile int dummy = 0;
    // move enc out
    // (we re-declare below using h3s captured here)
    // -- handled by moving decoder into same function scope:
    // store enc:
    // (simply continue using h3s)
    // ======================= DECODER =======================
    const float enc = h3s;

    float p1, wd1h[4];
    {
      const int g = lane & 15;                       // d1: din=1, h=4
      float wi = d1Wi[g]*A2;
      #pragma unroll
      for (int k=0;k<4;++k) wd1h[k] = d1Wh[g*4+k]*A2;
      p1 = fmaf(wi, enc, (d1bi[g] + d1bh[g])*A2);    // constant over t
    }
    float wd2i[4], wd2h[8], bd2;
    {
      const int g = lane & 31;                       // d2: din=4, h=8
      #pragma unroll
      for (int k=0;k<4;++k) wd2i[k] = d2Wi[g*4+k]*AD2;
      #pragma unroll
      for (int k=0;k<8;++k) wd2h[k] = d2Wh[g*8+k]*AD2;
      bd2 = (d2bi[g] + d2bh[g])*AD2;
    }
    float wd3i[8], wd3h[16], bd3;
    {
      const int g = lane;                            // d3: din=8, h=16
      #pragma unroll
      for (int k=0;k<8;++k)  wd3i[k] = d3Wi[g*8+k]*A1;
      #pragma unroll
      for (int k=0;k<16;++k) wd3h[k] = d3Wh[g*16+k]*A1;
      bd3 = (d3bi[g] + d3bh[g])*A1;
    }
    float wo[16], bo;
    {
      const int g = lane & 31;                       // final linear: 32 outputs
      #pragma unroll
      for (int k=0;k<16;++k) wo[k] = Wout[g*16+k];
      bo = bout[g];
    }

    float hd1[4], hd2[8], hd3[16];
    #pragma unroll
    for (int k=0;k<4;++k)  hd1[k] = 0.f;
    #pragma unroll
    for (int k=0;k<8;++k)  hd2[k] = 0.f;
    #pragma unroll
    for (int k=0;k<16;++k) hd3[k] = 0.f;
    float dc1 = 0.f, dc2 = 0.f, dc3 = 0.f;

    #pragma unroll 2
    for (int t=0;t<128;++t){
      // ---- d1: din=1 (constant input term), h=4
      float a0 = p1, a1 = 0.f;
      #pragma unroll
      for (int k=0;k<4;k+=2){ a0 = fmaf(wd1h[k], hd1[k], a0); a1 = fmaf(wd1h[k+1], hd1[k+1], a1); }
      float v = fmaf(sigm(a0+a1), A2, B2);
      float f = swx<4>(v);  float g = swx<8>(v);  float o = swx<12>(v);
      dc1 = fmaf(f, dc1, v*g);                      // valid lanes 0..3
      float h1 = o * tanh_f(dc1);
      #pragma unroll
      for (int k=0;k<4;++k) hd1[k] = rl(h1, k);

      // ---- d2: din=4, h=8
      a0 = bd2; a1 = 0.f;
      #pragma unroll
      for (int k=0;k<4;k+=2){ a0 = fmaf(wd2i[k], hd1[k], a0); a1 = fmaf(wd2i[k+1], hd1[k+1], a1); }
      #pragma unroll
      for (int k=0;k<8;k+=2){ a0 = fmaf(wd2h[k], hd2[k], a0); a1 = fmaf(wd2h[k+1], hd2[k+1], a1); }
      v = fmaf(sigm(a0+a1), AD2, BD2);
      f = swx<8>(v);  g = swx<16>(v);  o = swx<24>(v);
      dc2 = fmaf(f, dc2, v*g);                      // valid lanes 0..7
      float h2 = o * tanh_f(dc2);
      #pragma unroll
      for (int k=0;k<8;++k) hd2[k] = rl(h2, k);

      // ---- d3: din=8, h=16
      a0 = bd3; a1 = 0.f; float a2 = 0.f, a3 = 0.f;
      #pragma unroll
      for (int k=0;k<8;k+=4){
        a0 = fmaf(wd3i[k  ], hd2[k  ], a0);
        a1 = fmaf(wd3i[k+1], hd2[k+1], a1);
        a2 = fmaf(wd3i[k+2], hd2[k+2], a2);
        a3 = fmaf(wd3i[k+3], hd2[k+3], a3);
      }
      #pragma unroll
      for (int k=0;k<16;k+=4){
        a0 = fmaf(wd3h[k  ], hd3[k  ], a0);
        a1 = fmaf(wd3h[k+1], hd3[k+1], a1);
        a2 = fmaf(wd3h[k+2], hd3[k+2], a2);
        a3 = fmaf(wd3h[k+3], hd3[k+3], a3);
      }
      v = fmaf(sigm((a0+a1)+(a2+a3)), A1, B1);
      f = swx<16>(v);
      g = __shfl_xor(v, 32, 64);
      o = __shfl_xor(f, 32, 64);
      dc3 = fmaf(f, dc3, v*g);                      // valid lanes 0..15
      float h3 = o * tanh_f(dc3);
      #pragma unroll
      for (int k=0;k<16;++k) hd3[k] = rl(h3, k);

      // ---- final linear 16->32, coalesced store
      float ov0 = bo, ov1 = 0.f;
      #pragma unroll
      for (int k=0;k<16;k+=2){ ov0 = fmaf(wo[k], hd3[k], ov0); ov1 = fmaf(wo[k+1], hd3[k+1], ov1); }
      if (lane < 32) ob[t*32 + lane] = ov0 + ov1;
    }
  }
}

extern "C" void kernel_launch(void* const* d_in, const int* in_sizes, int n_in,
                              void* d_out, int out_size, void* d_ws, size_t ws_size,
                              hipStream_t stream) {
  (void)in_sizes; (void)n_in; (void)d_ws; (void)ws_size; (void)out_size;
  const float* x    = (const float*)d_in[0];
  const float* e1Wi = (const float*)d_in[1];
  const float* e1Wh = (const float*)d_in[2];
  const float* e1bi = (const float*)d_in[3];
  const float* e1bh = (const float*)d_in[4];
  const float* e2Wi = (const float*)d_in[5];
  const float* e2Wh = (const float*)d_in[6];
  const float* e2bi = (const float*)d_in[7];
  const float* e2bh = (const float*)d_in[8];
  const float* e3Wi = (const float*)d_in[9];
  const float* e3Wh = (const float*)d_in[10];
  const float* e3bi = (const float*)d_in[11];
  const float* e3bh = (const float*)d_in[12];
  const float* d1Wi = (const float*)d_in[13];
  const float* d1Wh = (const float*)d_in[14];
  const float* d1bi = (const float*)d_in[15];
  const float* d1bh = (const float*)d_in[16];
  const float* d2Wi = (const float*)d_in[17];
  const float* d2Wh = (const float*)d_in[18];
  const float* d2bi = (const float*)d_in[19];
  const float* d2bh = (const float*)d_in[20];
  const float* d3Wi = (const float*)d_in[21];
  const float* d3Wh = (const float*)d_in[22];
  const float* d3bi = (const float*)d_in[23];
  const float* d3bh = (const float*)d_in[24];
  const float* Wout = (const float*)d_in[25];
  const float* boutp= (const float*)d_in[26];
  float* out = (float*)d_out;

  lstm_ae_fused<<<4096, 64, 0, stream>>>(x,
      e1Wi, e1Wh, e1bi, e1bh,
      e2Wi, e2Wh, e2bi, e2bh,
      e3Wi, e3Wh, e3bi, e3bh,
      d1Wi, d1Wh, d1bi, d1bh,
      d2Wi, d2Wh, d2bi, d2bh,
      d3Wi, d3Wh, d3bi, d3bh,
      Wout, boutp, out);
}